// Round 7
// baseline (55.478 us; speedup 1.0000x reference)
//
#include <hip/hip_runtime.h>

// MPS batched contraction: out[b] = (e0^T * Π_i M_i(x[b,i]))[0]
// Per site (transposed GEMM, 16x16x32 f16 MFMA), verified R6:
//   A-op frag (dhalf,khalf): row d=16*dhalf+(lane&15), k=32*khalf+(lane>>4)*8+e
//   B-op (U) frag khalf:     col b=lane&15,            same k mapping
//   C/D: col=lane&15, row(l)=(lane>>4)*4+reg
//   U_khalf[e] = left[(lane>>4)*4+(e>>1) (+16 for khalf1)] * x[e&1]  (same lane)
//
// R7: PIPELINE PARALLELISM over sites. R1-R6 all obeyed waves/CU x rows/wave
// = 256, so per-site A-frag delivery cost (4KB x waves through LDS or L2)
// scaled with TLP -- a structural trap (16-row waves: 64KB/site/CU > 500cy).
// Instead: wave w holds sites [8w,8w+8) A-frags PERMANENTLY in VGPRs (128
// regs, loaded once; steady-state A traffic = 0). Tiles of 16 batch rows
// flow through the 8-wave pipeline; handoff = 32-float left-state per row
// via LDS (lane L of wave w-1 -> lane L of wave w), double-buffered by step
// parity, one barrier per step. 16 tiles + 7 fill = 23 steps.

typedef _Float16 half8 __attribute__((ext_vector_type(8)));
typedef float floatx4 __attribute__((ext_vector_type(4)));
typedef float f32x2 __attribute__((ext_vector_type(2)));

#define NSITES 64
#define WAVES 8
#define SPW 8                      // sites per wave
#define TILE 16                    // batch rows per tile
#define TILES 16                   // tiles per block (256 rows/block)
#define RSTRIDE 36                 // padded floats per row in state buffer
#define BNDSZ (TILE * RSTRIDE)     // 576 floats per (parity, boundary)

// Pre-pack A (fp32 [64][32][2][32]) -> fragment-ordered fp16 (same as R6).
// Af[((site*4+f)*64 + lane)*8 + e] = (f16) A[site][k>>1][k&1][d],
//   f = dhalf*2+khalf, d = 16*dhalf+(lane&15), k = 32*khalf+(lane>>4)*8+e
__global__ void mps_prep_afrag(const float* __restrict__ A, _Float16* __restrict__ Af) {
    __shared__ float sA[2048];
    const int site = blockIdx.x;
    const int tid  = threadIdx.x;
#pragma unroll
    for (int i = 0; i < 8; ++i) sA[tid + 256 * i] = A[site * 2048 + tid + 256 * i];
    __syncthreads();
    const int f     = tid >> 6;
    const int lane  = tid & 63;
    const int d     = 16 * (f >> 1) + (lane & 15);
    const int kbase = 32 * (f & 1) + (lane >> 4) * 8;
    half8 v;
#pragma unroll
    for (int e = 0; e < 8; ++e)
        v[e] = (_Float16)sA[(kbase + e) * 32 + d];
    reinterpret_cast<half8*>(Af)[(site * 4 + f) * 64 + lane] = v;
}

// U-frag from one left-state quad (f32 mul + RNE cvt; numerics identical
// to R1-R6, absmax 0.0117).
#define FRAGU(U, AC, X0, X1)                                                  \
    {                                                                         \
        U[0] = (_Float16)(AC[0] * (X0)); U[1] = (_Float16)(AC[0] * (X1));     \
        U[2] = (_Float16)(AC[1] * (X0)); U[3] = (_Float16)(AC[1] * (X1));     \
        U[4] = (_Float16)(AC[2] * (X0)); U[5] = (_Float16)(AC[2] * (X1));     \
        U[6] = (_Float16)(AC[3] * (X0)); U[7] = (_Float16)(AC[3] * (X1));     \
    }

// One site: A-frags AF[S][0..3] (f=dhalf*2+khalf) from persistent registers.
#define SITE(S, AI0, AI1, AO0, AO1, XB)                                       \
    {                                                                         \
        const float x0_ = XB[S][0], x1_ = XB[S][1];                           \
        half8 u0_, u1_;                                                       \
        FRAGU(u0_, AI0, x0_, x1_);                                            \
        FRAGU(u1_, AI1, x0_, x1_);                                            \
        AO0 = __builtin_amdgcn_mfma_f32_16x16x32_f16(AF[S][0], u0_, zv, 0, 0, 0);   \
        AO1 = __builtin_amdgcn_mfma_f32_16x16x32_f16(AF[S][2], u0_, zv, 0, 0, 0);   \
        AO0 = __builtin_amdgcn_mfma_f32_16x16x32_f16(AF[S][1], u1_, AO0, 0, 0, 0);  \
        AO1 = __builtin_amdgcn_mfma_f32_16x16x32_f16(AF[S][3], u1_, AO1, 0, 0, 0);  \
    }

// One pipeline step T (PAR = T&1 compile-time). Wave w processes tile T-w:
// read state (boundary w, parity PAR^1) or seed e0 (w==0); apply 8 sites;
// write state (boundary w+1, parity PAR) or final output (w==7).
// Prefetches next step's x (tile T+1-w) into XNXT first.
#define BODY(T, PAR, XCUR, XNXT)                                              \
    {                                                                         \
        const int tt_  = (T) - wid;                                           \
        const int ntt_ = (T) + 1 - wid;                                       \
        if (0 <= ntt_ && ntt_ < TILES) {                                      \
            const float* xb_ = x + ((size_t)(row0 + ntt_ * TILE + row)) * 128 \
                                 + wid * 16;                                  \
            _Pragma("unroll")                                                 \
            for (int s_ = 0; s_ < SPW; ++s_)                                  \
                XNXT[s_] = *(const f32x2*)(xb_ + 2 * s_);                     \
        }                                                                     \
        if (0 <= tt_ && tt_ < TILES) {                                        \
            floatx4 L0, L1, c0, c1, d0, d1;                                   \
            if (wid == 0) {                                                   \
                L0 = zv; L1 = zv;                                             \
                if (lane < 16) L0[0] = 1.f;    /* left0 = e0 */               \
            } else {                                                          \
                const float* rp_ = &st[(((PAR) ^ 1) * WAVES + wid) * BNDSZ    \
                                       + row * RSTRIDE];                      \
                L0 = *(const floatx4*)(rp_ + g4);                             \
                L1 = *(const floatx4*)(rp_ + 16 + g4);                        \
            }                                                                 \
            SITE(0, L0, L1, c0, c1, XCUR)                                     \
            SITE(1, c0, c1, d0, d1, XCUR)                                     \
            SITE(2, d0, d1, c0, c1, XCUR)                                     \
            SITE(3, c0, c1, d0, d1, XCUR)                                     \
            SITE(4, d0, d1, c0, c1, XCUR)                                     \
            SITE(5, c0, c1, d0, d1, XCUR)                                     \
            SITE(6, d0, d1, c0, c1, XCUR)                                     \
            SITE(7, c0, c1, d0, d1, XCUR)                                     \
            if (wid < WAVES - 1) {                                            \
                float* wp_ = &st[((PAR) * WAVES + wid + 1) * BNDSZ            \
                                 + row * RSTRIDE];                            \
                *(floatx4*)(wp_ + g4)      = d0;                              \
                *(floatx4*)(wp_ + 16 + g4) = d1;                              \
            } else if (lane < 16) {                                           \
                out[row0 + tt_ * TILE + lane] = d0[0];                        \
            }                                                                 \
        }                                                                     \
        __syncthreads();                                                      \
    }

__global__ __launch_bounds__(512) void mps_main(const float* __restrict__ x,
                                                const _Float16* __restrict__ Af,
                                                float* __restrict__ out) {
    // state handoff: 2 parities x 8 boundaries x (16 rows x 36 floats)
    __shared__ float st[2 * WAVES * BNDSZ];          // 36864 B

    const int lane = threadIdx.x & 63;
    const int wid  = threadIdx.x >> 6;               // pipeline stage 0..7
    const int row  = lane & 15;                      // batch row within tile
    const int g4   = (lane >> 4) * 4;                // l-quad base
    const int row0 = blockIdx.x * (TILES * TILE);    // 256 rows per block

    const half8* ap = reinterpret_cast<const half8*>(Af);

    floatx4 zv;
#pragma unroll
    for (int i = 0; i < 4; ++i) zv[i] = 0.f;

    // Persistent A-frags: this wave's 8 sites, 128 VGPRs, loaded once.
    half8 AF[SPW][4];
#pragma unroll
    for (int s = 0; s < SPW; ++s)
#pragma unroll
        for (int f = 0; f < 4; ++f)
            AF[s][f] = ap[((wid * SPW + s) * 4 + f) * 64 + lane];

    // x per-site (x0,x1) pairs, double-buffered across steps.
    f32x2 xa[SPW], xb[SPW];
#pragma unroll
    for (int s = 0; s < SPW; ++s) { xa[s][0] = 0.f; xa[s][1] = 0.f; }
    if (wid == 0) {                                  // step 0 is tile 0 on wave 0
        const float* xb0 = x + ((size_t)(row0 + row)) * 128 + wid * 16;
#pragma unroll
        for (int s = 0; s < SPW; ++s) xa[s] = *(const f32x2*)(xb0 + 2 * s);
    }
    __syncthreads();                                 // AF/LDS init fence

    // 24 steps (23 live + 1 idle tail), unrolled x2 for parity/buffer names.
    for (int it = 0; it < 12; ++it) {
        const int t0 = 2 * it;
        BODY(t0,     0, xa, xb)
        BODY(t0 + 1, 1, xb, xa)
    }
}

extern "C" void kernel_launch(void* const* d_in, const int* in_sizes, int n_in,
                              void* d_out, int out_size, void* d_ws, size_t ws_size,
                              hipStream_t stream) {
    const float* x = (const float*)d_in[0];   // [65536][64][2] f32
    const float* A = (const float*)d_in[1];   // [64][32][2][32] f32
    float* outp = (float*)d_out;              // [65536] f32
    _Float16* Af = (_Float16*)d_ws;           // 256 KB fragment-ordered fp16

    hipLaunchKernelGGL(mps_prep_afrag, dim3(NSITES), dim3(256), 0, stream, A, Af);
    hipLaunchKernelGGL(mps_main, dim3(65536 / (TILES * TILE)), dim3(512), 0, stream, x, Af, outp);
}

// Round 8
// 40.078 us; speedup vs baseline: 1.3843x; 1.3843x over previous
//
#include <hip/hip_runtime.h>

// MPS batched contraction: out[b] = (e0^T * Π_i M_i(x[b,i]))[0]
// Per site (transposed GEMM, 16x16x32 f16 MFMA), layout verified by R6 pass:
//   A-op frag (dhalf,khalf): row d=16*dhalf+(lane&15), k=32*khalf+(lane>>4)*8+e
//   B-op (U) frag khalf:     col b=lane&15,            same k mapping
//   C/D: col=lane&15, row(l)=(lane>>4)*4+reg
//   U_khalf[e] = left[l=(lane>>4)*4+(e>>1) (+16 if khalf1)] * x[e&1] (same lane)
//
// R8: dual-tile waves. R1-R7 localized the cost stack: (a) LDS A-frag
// delivery scales with waves/CU (each wave re-reads 4KB/site); (b) U-frag
// VALU; (c) chain latency at low TLP. Fix all three at once: each wave
// processes TWO 16-row tiles with the SAME A-frag registers (A-frag LDS
// traffic halves vs R6: 8 waves/CU x 4KB = 32KB/site), giving 2 independent
// MFMA chains/wave x 2 waves/SIMD = 4 chains/SIMD for latency hiding.
// 512 blocks of 256 thr (2 blocks/CU -> unaligned barriers overlap the
// vmcnt drain), LDS double-buffered 8-site chunks via global_load_lds.

typedef _Float16 half8 __attribute__((ext_vector_type(8)));
typedef float floatx4 __attribute__((ext_vector_type(4)));
typedef float f32x4 __attribute__((ext_vector_type(4)));

#define NSITES 64
// LDS chunk: 8 sites * 4 frags * (64 lanes * 8 halfs) = 16384 halfs = 32KB
#define CHUNK_ELEMS 16384

// Pre-pack A (fp32 [64][32][2][32]) -> fragment-ordered fp16 (same as R6).
// Af[((site*4+f)*64 + lane)*8 + e] = (f16) A[site][k>>1][k&1][d],
//   f = dhalf*2+khalf, d = 16*dhalf+(lane&15), k = 32*khalf+(lane>>4)*8+e
__global__ void mps_prep_afrag(const float* __restrict__ A, _Float16* __restrict__ Af) {
    __shared__ float sA[2048];
    const int site = blockIdx.x;
    const int tid  = threadIdx.x;
#pragma unroll
    for (int i = 0; i < 8; ++i) sA[tid + 256 * i] = A[site * 2048 + tid + 256 * i];
    __syncthreads();
    const int f     = tid >> 6;
    const int lane  = tid & 63;
    const int d     = 16 * (f >> 1) + (lane & 15);
    const int kbase = 32 * (f & 1) + (lane >> 4) * 8;
    half8 v;
#pragma unroll
    for (int e = 0; e < 8; ++e)
        v[e] = (_Float16)sA[(kbase + e) * 32 + d];
    reinterpret_cast<half8*>(Af)[(site * 4 + f) * 64 + lane] = v;
}

// U-frag from one acc half (f32 mul + RNE cvt; numerics identical to R1-R7,
// absmax 0.0117).
#define FRAGU(U, AC, X0, X1)                                                  \
    {                                                                         \
        U[0] = (_Float16)(AC[0] * (X0)); U[1] = (_Float16)(AC[0] * (X1));     \
        U[2] = (_Float16)(AC[1] * (X0)); U[3] = (_Float16)(AC[1] * (X1));     \
        U[4] = (_Float16)(AC[2] * (X0)); U[5] = (_Float16)(AC[2] * (X1));     \
        U[6] = (_Float16)(AC[3] * (X0)); U[7] = (_Float16)(AC[3] * (X1));     \
    }

#define MFMA16(A_, B_, C_) __builtin_amdgcn_mfma_f32_16x16x32_f16(A_, B_, C_, 0, 0, 0)

// One site for BOTH tiles. SL[4] = this site's A-frags (f=dhalf*2+khalf),
// shared by the two tiles. I0*/O0* = tile0 acc halves, I1*/O1* = tile1.
// XT0[2J],XT0[2J+1] = tile0 (x0,x1); XT1 likewise.
#define SITE(SL, I00, I01, I10, I11, O00, O01, O10, O11, XT0, XT1, J)         \
    {                                                                         \
        const float p0_ = XT0[2 * (J)], p1_ = XT0[2 * (J) + 1];               \
        const float q0_ = XT1[2 * (J)], q1_ = XT1[2 * (J) + 1];               \
        half8 u00_, u01_, u10_, u11_;                                         \
        FRAGU(u00_, I00, p0_, p1_);                                           \
        FRAGU(u01_, I01, p0_, p1_);                                           \
        FRAGU(u10_, I10, q0_, q1_);                                           \
        FRAGU(u11_, I11, q0_, q1_);                                           \
        O00 = MFMA16(SL[0], u00_, zv);  O01 = MFMA16(SL[2], u00_, zv);        \
        O10 = MFMA16(SL[0], u10_, zv);  O11 = MFMA16(SL[2], u10_, zv);        \
        O00 = MFMA16(SL[1], u01_, O00); O01 = MFMA16(SL[3], u01_, O01);       \
        O10 = MFMA16(SL[1], u11_, O10); O11 = MFMA16(SL[3], u11_, O11);       \
    }

// even site: a->n, odd site: n->a (ping-pong, no copies)
#define SITE_E(SL, XT0, XT1, J) SITE(SL, pa0, pa1, qa0, qa1, pn0, pn1, qn0, qn1, XT0, XT1, J)
#define SITE_O(SL, XT0, XT1, J) SITE(SL, pn0, pn1, qn0, qn1, pa0, pa1, qa0, qa1, XT0, XT1, J)

// Read site S (local to LDS buffer BUF) frags into register slot DST.
#define RDFRAG(DST, BUF, S)                                                   \
    {                                                                         \
        _Pragma("unroll")                                                     \
        for (int f_ = 0; f_ < 4; ++f_)                                        \
            DST[f_] = *(const half8*)&smA[BUF][(((S) * 4 + f_) * 64 + lane) * 8]; \
    }

// Stage chunk C (8 sites, 32 records of 1KB) into LDS buffer BUF.
// 4 waves x 8 records. LDS dest wave-uniform (+lane*16 by HW); src per-lane.
#define STAGE(C, BUF)                                                         \
    {                                                                         \
        _Pragma("unroll")                                                     \
        for (int r_ = 0; r_ < 8; ++r_) {                                      \
            const int rec_ = r_ * 4 + wid;                                    \
            const _Float16* g_ = Af + (size_t)(C) * CHUNK_ELEMS + rec_ * 512 + lane * 8; \
            __builtin_amdgcn_global_load_lds(                                 \
                (const __attribute__((address_space(1))) void*)g_,            \
                (__attribute__((address_space(3))) void*)&smA[BUF][rec_ * 512], \
                16, 0, 0);                                                    \
        }                                                                     \
    }

// Load x pair-of-sites P (4 floats) for both tiles.
#define LOADP(DA, DB, P)                                                      \
    {                                                                         \
        f32x4 ta_ = xp0[(P) & 31];                                            \
        f32x4 tb_ = xp1[(P) & 31];                                            \
        DA[0] = ta_[0]; DA[1] = ta_[1]; DA[2] = ta_[2]; DA[3] = ta_[3];       \
        DB[0] = tb_[0]; DB[1] = tb_[1]; DB[2] = tb_[2]; DB[3] = tb_[3];       \
    }

// One 8-site chunk reading LDS buffer BUF; stages chunk C+1 into the other
// buffer up front; x pair-buffers ping-pong (xA = current pair, xB = next).
#define CHUNK(C, BUF, DO_NEXT)                                                \
    {                                                                         \
        if (DO_NEXT) STAGE((C) + 1, 1 - (BUF));                               \
        LOADP(xB0, xB1, 4 * (C) + 1)                                          \
        SITE_E(F0, xA0, xA1, 0) RDFRAG(F0, BUF, 2)                            \
        SITE_O(F1, xA0, xA1, 1) RDFRAG(F1, BUF, 3)                            \
        LOADP(xA0, xA1, 4 * (C) + 2)                                          \
        SITE_E(F0, xB0, xB1, 0) RDFRAG(F0, BUF, 4)                            \
        SITE_O(F1, xB0, xB1, 1) RDFRAG(F1, BUF, 5)                            \
        LOADP(xB0, xB1, 4 * (C) + 3)                                          \
        SITE_E(F0, xA0, xA1, 0) RDFRAG(F0, BUF, 6)                            \
        SITE_O(F1, xA0, xA1, 1) RDFRAG(F1, BUF, 7)                            \
        LOADP(xA0, xA1, 4 * (C) + 4)                                          \
        SITE_E(F0, xB0, xB1, 0)                                               \
        SITE_O(F1, xB0, xB1, 1)                                               \
        __syncthreads();                                                      \
        if (DO_NEXT) { RDFRAG(F0, 1 - (BUF), 0) RDFRAG(F1, 1 - (BUF), 1) }    \
    }

__global__ __launch_bounds__(256, 2) void mps_main(const float* __restrict__ x,
                                                   const _Float16* __restrict__ Af,
                                                   float* __restrict__ out) {
    __shared__ __align__(16) _Float16 smA[2][CHUNK_ELEMS];   // 2 x 32KB

    const int lane  = threadIdx.x & 63;
    const int wid   = threadIdx.x >> 6;               // 0..3
    const int wbase = (blockIdx.x * 4 + wid) * 32;    // 32 batch rows per wave
    const int r     = lane & 15;
    const int b0    = wbase + r;                      // tile0 row
    const int b1    = wbase + 16 + r;                 // tile1 row

    const f32x4* xp0 = reinterpret_cast<const f32x4*>(x + (size_t)b0 * (NSITES * 2));
    const f32x4* xp1 = reinterpret_cast<const f32x4*>(x + (size_t)b1 * (NSITES * 2));

    floatx4 zv;
#pragma unroll
    for (int i = 0; i < 4; ++i) zv[i] = 0.f;

    // acc: p* = tile0 (halves 0,1 = l 0..15 / 16..31), q* = tile1
    floatx4 pa0, pa1, qa0, qa1, pn0, pn1, qn0, qn1;
#pragma unroll
    for (int i = 0; i < 4; ++i) {
        pa0[i] = 0.f; pa1[i] = 0.f; qa0[i] = 0.f; qa1[i] = 0.f;
        pn0[i] = 0.f; pn1[i] = 0.f; qn0[i] = 0.f; qn1[i] = 0.f;
    }
    if (lane < 16) { pa0[0] = 1.f; qa0[0] = 1.f; }    // left0 = e0

    float xA0[4], xA1[4], xB0[4], xB1[4];
    half8 F0[4], F1[4];

    STAGE(0, 0);
    LOADP(xA0, xA1, 0)
    __syncthreads();
    RDFRAG(F0, 0, 0)
    RDFRAG(F1, 0, 1)

    CHUNK(0, 0, 1)
    CHUNK(1, 1, 1)
    CHUNK(2, 0, 1)
    CHUNK(3, 1, 1)
    CHUNK(4, 0, 1)
    CHUNK(5, 1, 1)
    CHUNK(6, 0, 1)
    CHUNK(7, 1, 0)

    // out[b] = left_final[l=0]: half0 reg0 at lane group 0
    if (lane < 16) {
        out[wbase + lane]      = pa0[0];
        out[wbase + 16 + lane] = qa0[0];
    }
}

extern "C" void kernel_launch(void* const* d_in, const int* in_sizes, int n_in,
                              void* d_out, int out_size, void* d_ws, size_t ws_size,
                              hipStream_t stream) {
    const float* x = (const float*)d_in[0];   // [65536][64][2] f32
    const float* A = (const float*)d_in[1];   // [64][32][2][32] f32
    float* outp = (float*)d_out;              // [65536] f32
    _Float16* Af = (_Float16*)d_ws;           // 256 KB fragment-ordered fp16

    hipLaunchKernelGGL(mps_prep_afrag, dim3(NSITES), dim3(256), 0, stream, A, Af);
    hipLaunchKernelGGL(mps_main, dim3(65536 / 128), dim3(256), 0, stream, x, Af, outp);
}

// Round 9
// 31.871 us; speedup vs baseline: 1.7407x; 1.2575x over previous
//
#include <hip/hip_runtime.h>

// MPS batched contraction via SITE PAIRING: out[b] = (e0^T Π_i M_i(x_b,i))[0],
// M_i linear in x => pair product  left'' = G_P(xx) left  with
// G_P[l][pq][d] = Σ_m A_{2P}[l,p,m] A_{2P+1}[m,q,d],  xx[pq] = x_p * y_q.
// 32 pairs of K=128 GEMMs (16x16x32 f16 MFMA, 4 kh frags x 2 d-halves).
// k-mapping k = 32*kh + 8*g + (l&3) + 4*(l>>4)  (g = lane>>4) makes the
// U-fragment SAME-LANE: U_kh[e] = f16(acc_{e>>2}[e&3]) * xx[kh]  -- the f16
// acc is shared across all 4 frags (8 cvt + 16 v_pk_mul_f16 per tile).
// Halves chain hops (32) and per-site VALU vs R6/R8; G bytes unchanged.

typedef _Float16 h2 __attribute__((ext_vector_type(2)));
typedef _Float16 half8 __attribute__((ext_vector_type(8)));
typedef float floatx4 __attribute__((ext_vector_type(4)));
typedef float f32x4 __attribute__((ext_vector_type(4)));

#define NPAIRS 32
#define CHUNK_ELEMS 16384   // 4 pairs * 8 frags * 64 lanes * 8 halfs = 32KB

// ---------------- prep: pair products + fragment packing ----------------
// Gf frag (P, fr=dh*4+kh): elem e of lane = G_P[l][kh][d], d = 16*dh+(lane&15),
// l = 4*(lane>>4) + (e&3) + 16*(e>>2).
__global__ void mps_prep_pair(const float* __restrict__ A, _Float16* __restrict__ Gf) {
    __shared__ float sA0[2048], sA1[2048], sG[4096];
    const int P = blockIdx.x, tid = threadIdx.x;
    const float* a0p = A + (size_t)(2 * P) * 2048;
    const float* a1p = A + (size_t)(2 * P + 1) * 2048;
#pragma unroll
    for (int i = 0; i < 8; ++i) {
        sA0[tid + 256 * i] = a0p[tid + 256 * i];
        sA1[tid + 256 * i] = a1p[tid + 256 * i];
    }
    __syncthreads();
    {   // thread -> (l, pq, d-half): 16 outputs, dot over m=32 in f32
        const int l = tid >> 3, pq = (tid >> 1) & 3, dh16 = (tid & 1) * 16;
        const int p = pq >> 1, q = pq & 1;
        float accv[16];
#pragma unroll
        for (int dd = 0; dd < 16; ++dd) accv[dd] = 0.f;
        for (int m = 0; m < 32; ++m) {
            const float av = sA0[l * 64 + p * 32 + m];
            const float* bp = &sA1[m * 64 + q * 32 + dh16];
#pragma unroll
            for (int dd = 0; dd < 16; ++dd) accv[dd] += av * bp[dd];
        }
#pragma unroll
        for (int dd = 0; dd < 16; ++dd) sG[l * 128 + pq * 32 + dh16 + dd] = accv[dd];
    }
    __syncthreads();
    const int lane = tid & 63, g = lane >> 4;
#pragma unroll
    for (int pass = 0; pass < 2; ++pass) {
        const int fr = (tid >> 6) + pass * 4;      // 0..7
        const int dh = fr >> 2, kh = fr & 3;
        const int d  = 16 * dh + (lane & 15);
        half8 v;
#pragma unroll
        for (int e = 0; e < 8; ++e) {
            const int l = 4 * g + (e & 3) + 16 * (e >> 2);
            v[e] = (_Float16)sG[l * 128 + kh * 32 + d];
        }
        reinterpret_cast<half8*>(Gf)[((size_t)P * 8 + fr) * 64 + lane] = v;
    }
}

// ---------------- main kernel ----------------
static __device__ __forceinline__ half8 H8(h2 a, h2 b, h2 c, h2 d) {
    half8 r;
    r[0] = a[0]; r[1] = a[1]; r[2] = b[0]; r[3] = b[1];
    r[4] = c[0]; r[5] = c[1]; r[6] = d[0]; r[7] = d[1];
    return r;
}

#define MF(A_, B_, C_) __builtin_amdgcn_mfma_f32_16x16x32_f16(A_, B_, C_, 0, 0, 0)

// U-frags for one tile from acc halves (AH0 = l 0..15, AH1 = l 16..31) and
// this pair's x quad XV = (x0,x1,y0,y1).  8 cvt + 4 mul + 4 cvt + 16 pk_mul.
#define UB(U0, U1, U2, U3, AH0, AH1, XV)                                      \
    {                                                                         \
        h2 b0, b1, b2, b3, w0, w1, w2, w3;                                    \
        b0[0] = (_Float16)AH0[0]; b0[1] = (_Float16)AH0[1];                   \
        b1[0] = (_Float16)AH0[2]; b1[1] = (_Float16)AH0[3];                   \
        b2[0] = (_Float16)AH1[0]; b2[1] = (_Float16)AH1[1];                   \
        b3[0] = (_Float16)AH1[2]; b3[1] = (_Float16)AH1[3];                   \
        _Float16 t_;                                                          \
        t_ = (_Float16)(XV[0] * XV[2]); w0[0] = t_; w0[1] = t_;               \
        t_ = (_Float16)(XV[0] * XV[3]); w1[0] = t_; w1[1] = t_;               \
        t_ = (_Float16)(XV[1] * XV[2]); w2[0] = t_; w2[1] = t_;               \
        t_ = (_Float16)(XV[1] * XV[3]); w3[0] = t_; w3[1] = t_;               \
        U0 = H8(b0 * w0, b1 * w0, b2 * w0, b3 * w0);                          \
        U1 = H8(b0 * w1, b1 * w1, b2 * w1, b3 * w1);                          \
        U2 = H8(b0 * w2, b1 * w2, b2 * w2, b3 * w2);                          \
        U3 = H8(b0 * w3, b1 * w3, b2 * w3, b3 * w3);                          \
    }

// One pair for BOTH tiles. G[fr]: fr = dh*4+kh. 16 MFMA (2 tiles x 2 dh x 4 kh).
#define PAIR(G, I00, I01, I10, I11, O00, O01, O10, O11, XV0, XV1)             \
    {                                                                         \
        half8 u0_, u1_, u2_, u3_, v0_, v1_, v2_, v3_;                         \
        UB(u0_, u1_, u2_, u3_, I00, I01, XV0)                                 \
        UB(v0_, v1_, v2_, v3_, I10, I11, XV1)                                 \
        O00 = MF(G[0], u0_, zv);  O01 = MF(G[4], u0_, zv);                    \
        O10 = MF(G[0], v0_, zv);  O11 = MF(G[4], v0_, zv);                    \
        O00 = MF(G[1], u1_, O00); O01 = MF(G[5], u1_, O01);                   \
        O10 = MF(G[1], v1_, O10); O11 = MF(G[5], v1_, O11);                   \
        O00 = MF(G[2], u2_, O00); O01 = MF(G[6], u2_, O01);                   \
        O10 = MF(G[2], v2_, O10); O11 = MF(G[6], v2_, O11);                   \
        O00 = MF(G[3], u3_, O00); O01 = MF(G[7], u3_, O01);                   \
        O10 = MF(G[3], v3_, O10); O11 = MF(G[7], v3_, O11);                   \
    }

// Read pair PL (local to chunk buffer BUF) 8 frags into register slot DST.
#define RD(DST, BUF, PL)                                                      \
    {                                                                         \
        _Pragma("unroll")                                                     \
        for (int f_ = 0; f_ < 8; ++f_)                                        \
            DST[f_] = *(const half8*)&smA[(BUF) * CHUNK_ELEMS                 \
                                          + (((PL) * 8 + f_) * 64 + lane) * 8]; \
    }

// Stage chunk C (4 pairs, 32 recs of 1KB) into buffer BUF. 4 waves x 8 recs.
#define STAGE(C, BUF)                                                         \
    {                                                                         \
        _Pragma("unroll")                                                     \
        for (int r_ = 0; r_ < 8; ++r_) {                                      \
            const int rec_ = r_ * 4 + wid;                                    \
            const _Float16* g_ = Gf + (size_t)(C) * CHUNK_ELEMS               \
                                 + rec_ * 512 + lane * 8;                     \
            __builtin_amdgcn_global_load_lds(                                 \
                (const __attribute__((address_space(1))) void*)g_,            \
                (__attribute__((address_space(3))) void*)&smA[(BUF) * CHUNK_ELEMS + rec_ * 512], \
                16, 0, 0);                                                    \
        }                                                                     \
    }

// One 4-pair chunk: stage next chunk + prefetch next x up front, 2-slot
// register G pipeline (GA/GB), barrier, then pre-read next chunk's pair 0.
#define CHUNKB(C, BUF, XC0, XC1, XN0, XN1)                                    \
    {                                                                         \
        if ((C) < 7) {                                                        \
            STAGE((C) + 1, 1 - (BUF));                                        \
            _Pragma("unroll")                                                 \
            for (int pp_ = 0; pp_ < 4; ++pp_) {                               \
                XN0[pp_] = xp0[4 * ((C) + 1) + pp_];                          \
                XN1[pp_] = xp1[4 * ((C) + 1) + pp_];                          \
            }                                                                 \
        }                                                                     \
        RD(GB, BUF, 1)                                                        \
        PAIR(GA, p0, p1, q0, q1, np0, np1, nq0, nq1, XC0[0], XC1[0])          \
        RD(GA, BUF, 2)                                                        \
        PAIR(GB, np0, np1, nq0, nq1, p0, p1, q0, q1, XC0[1], XC1[1])          \
        RD(GB, BUF, 3)                                                        \
        PAIR(GA, p0, p1, q0, q1, np0, np1, nq0, nq1, XC0[2], XC1[2])          \
        PAIR(GB, np0, np1, nq0, nq1, p0, p1, q0, q1, XC0[3], XC1[3])          \
        __syncthreads();                                                      \
        if ((C) < 7) RD(GA, 1 - (BUF), 0)                                     \
    }

__global__ __launch_bounds__(256, 2) void mps_main(const float* __restrict__ x,
                                                   const _Float16* __restrict__ Gf,
                                                   float* __restrict__ out) {
    __shared__ __align__(16) _Float16 smA[2 * CHUNK_ELEMS];   // 64KB

    const int lane  = threadIdx.x & 63;
    const int wid   = threadIdx.x >> 6;               // 0..3
    const int wbase = (blockIdx.x * 4 + wid) * 32;    // 32 rows per wave (2 tiles)
    const int r     = lane & 15;
    const int b0    = wbase + r;
    const int b1    = wbase + 16 + r;

    const f32x4* xp0 = reinterpret_cast<const f32x4*>(x + (size_t)b0 * 128);
    const f32x4* xp1 = reinterpret_cast<const f32x4*>(x + (size_t)b1 * 128);

    floatx4 zv;
#pragma unroll
    for (int i = 0; i < 4; ++i) zv[i] = 0.f;

    // acc: tile0 = (p0,p1) = left[0..15],[16..31]; tile1 = (q0,q1); n* = partners
    floatx4 p0, p1, q0, q1, np0, np1, nq0, nq1;
#pragma unroll
    for (int i = 0; i < 4; ++i) {
        p0[i] = 0.f; p1[i] = 0.f; q0[i] = 0.f; q1[i] = 0.f;
        np0[i] = 0.f; np1[i] = 0.f; nq0[i] = 0.f; nq1[i] = 0.f;
    }
    if (lane < 16) { p0[0] = 1.f; q0[0] = 1.f; }      // left0 = e0

    f32x4 xa0[4], xa1[4], xb0[4], xb1[4];
    half8 GA[8], GB[8];

    STAGE(0, 0);
#pragma unroll
    for (int pp = 0; pp < 4; ++pp) { xa0[pp] = xp0[pp]; xa1[pp] = xp1[pp]; }
    __syncthreads();
    RD(GA, 0, 0)

    for (int it = 0; it < 4; ++it) {
        const int c0 = 2 * it;
        CHUNKB(c0,     0, xa0, xa1, xb0, xb1)
        CHUNKB(c0 + 1, 1, xb0, xb1, xa0, xa1)
    }

    // out[b] = left_final[0]: half0 reg0, lane group 0
    if (lane < 16) {
        out[wbase + lane]      = p0[0];
        out[wbase + 16 + lane] = q0[0];
    }
}

extern "C" void kernel_launch(void* const* d_in, const int* in_sizes, int n_in,
                              void* d_out, int out_size, void* d_ws, size_t ws_size,
                              hipStream_t stream) {
    const float* x = (const float*)d_in[0];   // [65536][64][2] f32
    const float* A = (const float*)d_in[1];   // [64][32][2][32] f32
    float* outp = (float*)d_out;              // [65536] f32
    _Float16* Gf = (_Float16*)d_ws;           // 256 KB pair-fragment fp16

    hipLaunchKernelGGL(mps_prep_pair, dim3(NPAIRS), dim3(256), 0, stream, A, Gf);
    hipLaunchKernelGGL(mps_main, dim3(65536 / 128), dim3(256), 0, stream, x, Gf, outp);
}